// Round 8
// baseline (151.874 us; speedup 1.0000x reference)
//
#include <hip/hip_runtime.h>
#include <math.h>

// B=1, L=512, D=1024, NH=16, NKV=4, NR=16, HD=RD=64
#define ATTN_SCALE 0.125f
#define REL_SCALE 0.125f

using ushort = unsigned short;
using bf16x8 = __attribute__((ext_vector_type(8))) __bf16;
using floatx4 = __attribute__((ext_vector_type(4))) float;
using ushort8 = __attribute__((ext_vector_type(8))) ushort;
using ushort4v = __attribute__((ext_vector_type(4))) ushort;

__device__ __forceinline__ ushort f2bf(float x) {
  unsigned int u = __builtin_bit_cast(unsigned int, x);
  u += 0x7fffu + ((u >> 16) & 1u);  // RNE
  return (ushort)(u >> 16);
}

// global -> LDS direct DMA, 16B per lane. LDS dest is wave-uniform base +
// lane*16 (HW semantics); global src is per-lane.
__device__ __forceinline__ void gload16(const ushort* src, ushort* lds) {
  __builtin_amdgcn_global_load_lds(
      (const __attribute__((address_space(1))) void*)src,
      (__attribute__((address_space(3))) void*)lds, 16, 0, 0);
}

// ---------------------------------------------------------------------------
// prep: z=0..5 weight transpose+convert; one-pass float4 loads, ushort4 (8B)
//       vectorized stores. z=6 x/symbols fp32->bf16.
// ---------------------------------------------------------------------------
__global__ __launch_bounds__(256) void prep_kernel(
    const float* __restrict__ x, const float* __restrict__ sym,
    const float* __restrict__ wq, const float* __restrict__ wk,
    const float* __restrict__ wqr, const float* __restrict__ wkr,
    const float* __restrict__ wv, const float* __restrict__ wo,
    ushort* __restrict__ xb, ushort* __restrict__ symb,
    ushort* __restrict__ wqT, ushort* __restrict__ wkT, ushort* __restrict__ wqrT,
    ushort* __restrict__ wkrT, ushort* __restrict__ wvT, ushort* __restrict__ woT) {
  if (blockIdx.z == 6) {
    int b = blockIdx.y * 32 + blockIdx.x;
    if (b >= 512) return;
    int idx = b * 256 + threadIdx.x;
    int i4 = idx << 2;
    float4 v = *(const float4*)(x + i4);
    uint2 o;
    o.x = (unsigned)f2bf(v.x) | ((unsigned)f2bf(v.y) << 16);
    o.y = (unsigned)f2bf(v.z) | ((unsigned)f2bf(v.w) << 16);
    *(uint2*)(xb + i4) = o;
    float4 w = *(const float4*)(sym + i4);
    o.x = (unsigned)f2bf(w.x) | ((unsigned)f2bf(w.y) << 16);
    o.y = (unsigned)f2bf(w.z) | ((unsigned)f2bf(w.w) << 16);
    *(uint2*)(symb + i4) = o;
    return;
  }
  __shared__ ushort t[32][44];
  const float* in;
  ushort* out;
  int N;
  switch (blockIdx.z) {
    case 0: in = wq;  out = wqT;  N = 1024; break;
    case 1: in = wk;  out = wkT;  N = 256;  break;
    case 2: in = wqr; out = wqrT; N = 1024; break;
    case 3: in = wkr; out = wkrT; N = 1024; break;
    case 4: in = wv;  out = wvT;  N = 256;  break;
    default: in = wo; out = woT;  N = 1024; break;
  }
  int n0 = blockIdx.x << 5;
  if (n0 >= N) return;
  int k0 = blockIdx.y << 5;
  {
    int kr = threadIdx.x >> 3, nq = threadIdx.x & 7;
    float4 v = *(const float4*)(in + (size_t)(k0 + kr) * N + n0 + (nq << 2));
    ushort4v c;
    c.x = f2bf(v.x); c.y = f2bf(v.y); c.z = f2bf(v.z); c.w = f2bf(v.w);
    *(ushort4v*)&t[kr][nq << 2] = c;
  }
  __syncthreads();
  {
    int nr = threadIdx.x >> 3, kq = threadIdx.x & 7;
    ushort4v c;
    c.x = t[(kq << 2) + 0][nr];
    c.y = t[(kq << 2) + 1][nr];
    c.z = t[(kq << 2) + 2][nr];
    c.w = t[(kq << 2) + 3][nr];
    *(ushort4v*)(out + (size_t)(n0 + nr) * 1024 + k0 + (kq << 2)) = c;
  }
}

// ---------------------------------------------------------------------------
// proj: 64x32 tiles, BK=128, DOUBLE-BUFFERED global_load_lds staging (T3
// 2-phase minimum): issue tile k+1's DMA before computing tile k; single
// barrier per K-step (compiler's vmcnt(0) drain lands after compute).
// XOR swizzle both sides (source colchunk ^= row&7; read col ^= (row&7)<<3).
// z = {q(+rope), k(+rope), qr, kr, sv(->svT)}.
// ---------------------------------------------------------------------------
__global__ __launch_bounds__(256) void proj_mfma(
    const ushort* __restrict__ xb, const ushort* __restrict__ symb,
    const ushort* __restrict__ wqT, const ushort* __restrict__ wkT,
    const ushort* __restrict__ wqrT, const ushort* __restrict__ wkrT,
    const ushort* __restrict__ wvT,
    ushort* __restrict__ qb, ushort* __restrict__ kb, ushort* __restrict__ qrb,
    ushort* __restrict__ krb, ushort* __restrict__ svT,
    const float* __restrict__ fcos, const float* __restrict__ fsin) {
  __shared__ ushort As[2][64][128];
  __shared__ ushort Bs[2][32][128];
  const int z = blockIdx.z;
  const ushort* A = xb;
  const ushort* Bt;
  ushort* C;
  int N;
  switch (z) {
    case 0: Bt = wqT;  C = qb;  N = 1024; break;
    case 1: Bt = wkT;  C = kb;  N = 256;  break;
    case 2: Bt = wqrT; C = qrb; N = 1024; break;
    case 3: Bt = wkrT; C = krb; N = 1024; break;
    default: A = symb; Bt = wvT; C = svT; N = 256; break;
  }
  const int bn = blockIdx.x << 5;
  if (bn >= N) return;
  const int bm = blockIdx.y << 6;
  const int tid = threadIdx.x;
  const int lane = tid & 63;
  const int wid = tid >> 6;  // wave 0..3
  const int wy = (tid >> 7) & 1, wx = (tid >> 6) & 1;
  const int lm = lane & 15, lq = lane >> 4;
  const int lrow = lane >> 4, lcol = lane & 15;  // within 1KB DMA chunk
  const int arow = 32 * wy + lm;
  const int brow = 16 * wx + lm;
  const int aswz = (arow & 7) << 3;
  const int bswz = (brow & 7) << 3;
  floatx4 acc[2] = {};

  auto stage = [&](int buf, int k0) {
#pragma unroll
    for (int c = 0; c < 4; ++c) {
      int row = 16 * wid + 4 * c + lrow;
      int cc = lcol ^ (row & 7);
      gload16(A + (size_t)(bm + row) * 1024 + k0 + cc * 8,
              &As[buf][16 * wid + 4 * c][0]);
    }
#pragma unroll
    for (int c = 0; c < 2; ++c) {
      int row = 8 * wid + 4 * c + lrow;
      int cc = lcol ^ (row & 7);
      gload16(Bt + (size_t)(bn + row) * 1024 + k0 + cc * 8,
              &Bs[buf][8 * wid + 4 * c][0]);
    }
  };
  auto compute = [&](int buf) {
#pragma unroll
    for (int kh = 0; kh < 4; ++kh) {
      int col = kh * 32 + lq * 8;
      bf16x8 a0 = *(const bf16x8*)&As[buf][arow][col ^ aswz];
      bf16x8 a1 = *(const bf16x8*)&As[buf][arow + 16][col ^ aswz];
      bf16x8 b0 = *(const bf16x8*)&Bs[buf][brow][col ^ bswz];
      acc[0] = __builtin_amdgcn_mfma_f32_16x16x32_bf16(a0, b0, acc[0], 0, 0, 0);
      acc[1] = __builtin_amdgcn_mfma_f32_16x16x32_bf16(a1, b0, acc[1], 0, 0, 0);
    }
  };

  stage(0, 0);
  __syncthreads();  // vmcnt(0) drain: buf0 ready
  int buf = 0;
  for (int k0 = 128; k0 < 1024; k0 += 128) {
    stage(buf ^ 1, k0);  // overlap next-tile DMA with this tile's MFMA
    compute(buf);
    __syncthreads();     // drains the new stage + syncs readers
    buf ^= 1;
  }
  compute(buf);

  if (z <= 1) {
    // fused RoPE: lanes lm, lm^1 hold the (even,odd) pair of d
#pragma unroll
    for (int sy = 0; sy < 2; ++sy)
#pragma unroll
      for (int e = 0; e < 4; ++e) {
        int row = bm + 32 * wy + 16 * sy + 4 * lq + e;
        int col = bn + 16 * wx + lm;
        float v = acc[sy][e];
        float pv = __shfl_xor(v, 1);
        int d = col & 63, p = d >> 1;
        float c = fcos[(row << 5) + p], s = fsin[(row << 5) + p];
        float o = (d & 1) ? fmaf(pv, s, v * c) : fmaf(v, c, -pv * s);
        C[(size_t)row * N + col] = f2bf(o);
      }
  } else if (z == 4) {
#pragma unroll
    for (int sy = 0; sy < 2; ++sy)
#pragma unroll
      for (int e = 0; e < 4; ++e) {
        int row = bm + 32 * wy + 16 * sy + 4 * lq + e;
        int col = bn + 16 * wx + lm;
        svT[(size_t)col * 512 + row] = f2bf(acc[sy][e]);
      }
  } else {
#pragma unroll
    for (int sy = 0; sy < 2; ++sy)
#pragma unroll
      for (int e = 0; e < 4; ++e) {
        int row = bm + 32 * wy + 16 * sy + 4 * lq + e;
        int col = bn + 16 * wx + lm;
        C[(size_t)row * N + col] = f2bf(acc[sy][e]);
      }
  }
}

// ---------------------------------------------------------------------------
// relflash: bx<512 -> flash; bx>=512 -> relations.
// ---------------------------------------------------------------------------
struct FlashSh {
  float S[16][516];
  ushort P[16][520];
};
union RelFlashSh {
  FlashSh f;
  ushort RT[32 * 648];  // [i(32)][r(16)][j(40 padded, 32 used)]
};

__global__ __launch_bounds__(256) void relflash_kernel(
    const ushort* __restrict__ qb, const ushort* __restrict__ kb,
    const ushort* __restrict__ svT, const ushort* __restrict__ qrb,
    const ushort* __restrict__ krb, float* __restrict__ attn,
    ushort* __restrict__ attn_b, float* __restrict__ asym,
    float* __restrict__ rel, ushort* __restrict__ rel_bT) {
  __shared__ RelFlashSh sh;
  const int bx = blockIdx.x;
  const int tid = threadIdx.x, wave = tid >> 6, lane = tid & 63;
  const int lm = lane & 15, lq = lane >> 4;
  if (bx >= 512) {
    // ---- relations ----
    const int b = bx - 512;
    const int bi0 = (b >> 4) << 5, bj0 = (b & 15) << 5;
    const int ib = bi0 + ((wave >> 1) << 4), jb = bj0 + ((wave & 1) << 4);
    const int il0 = (wave >> 1) << 4, jl0 = (wave & 1) << 4;
    const ushort* qrow = qrb + (size_t)(ib + lm) * 1024 + lq * 8;
    const ushort* krow = krb + (size_t)(jb + lm) * 1024 + lq * 8;
    floatx4 acc[16];
#pragma unroll
    for (int rq = 0; rq < 4; ++rq) {
#pragma unroll
      for (int rr = 0; rr < 4; ++rr) {
        int r = (rq << 2) + rr;
        int roff = r << 6;
        bf16x8 a0 = *(const bf16x8*)(qrow + roff);
        bf16x8 a1 = *(const bf16x8*)(qrow + roff + 32);
        bf16x8 b0 = *(const bf16x8*)(krow + roff);
        bf16x8 b1 = *(const bf16x8*)(krow + roff + 32);
        floatx4 t = {0.f, 0.f, 0.f, 0.f};
        t = __builtin_amdgcn_mfma_f32_16x16x32_bf16(a0, b0, t, 0, 0, 0);
        t = __builtin_amdgcn_mfma_f32_16x16x32_bf16(a1, b1, t, 0, 0, 0);
        acc[r] = t;
      }
    }
#pragma unroll
    for (int e = 0; e < 4; ++e) {
      int i = ib + 4 * lq + e, j = jb + lm;
      int il = il0 + 4 * lq + e, jl = jl0 + lm;
      float* dst = rel + ((size_t)i * 512 + j) * 16;
      ushort* rt = &sh.RT[il * 648 + jl];
#pragma unroll
      for (int q = 0; q < 4; ++q) {
        float4 v = make_float4(acc[4 * q + 0][e] * REL_SCALE,
                               acc[4 * q + 1][e] * REL_SCALE,
                               acc[4 * q + 2][e] * REL_SCALE,
                               acc[4 * q + 3][e] * REL_SCALE);
        *(float4*)(dst + (q << 2)) = v;
        rt[(4 * q + 0) * 40] = f2bf(v.x);
        rt[(4 * q + 1) * 40] = f2bf(v.y);
        rt[(4 * q + 2) * 40] = f2bf(v.z);
        rt[(4 * q + 3) * 40] = f2bf(v.w);
      }
    }
    __syncthreads();
    {
      const int r = lane >> 2, jq = lane & 3;
#pragma unroll
      for (int it2 = 0; it2 < 8; ++it2) {
        int il = (it2 << 2) + wave;
        ushort8 v = *(const ushort8*)&sh.RT[il * 648 + r * 40 + (jq << 3)];
        *(ushort8*)(rel_bT + (size_t)(bi0 + il) * 8192 + (size_t)r * 512 + bj0 +
                    (jq << 3)) = v;
      }
    }
    return;
  }
  // ---- flash ----
  const int h = bx >> 5, it = 31 - (bx & 31);  // longest tiles dispatched first
  const int i0 = it << 4, kv = h >> 2;
  const int ntiles = it + 1;
  const ushort* qrow = qb + (size_t)(i0 + lm) * 1024 + (h << 6) + lq * 8;
  bf16x8 a0 = *(const bf16x8*)(qrow);
  bf16x8 a1 = *(const bf16x8*)(qrow + 32);
  for (int jt = wave; jt < ntiles; jt += 4) {
    int jb = jt << 4;
    const ushort* krow = kb + (size_t)(jb + lm) * 256 + (kv << 6) + lq * 8;
    bf16x8 b0 = *(const bf16x8*)(krow);
    bf16x8 b1 = *(const bf16x8*)(krow + 32);
    floatx4 acc = {0.f, 0.f, 0.f, 0.f};
    acc = __builtin_amdgcn_mfma_f32_16x16x32_bf16(a0, b0, acc, 0, 0, 0);
    acc = __builtin_amdgcn_mfma_f32_16x16x32_bf16(a1, b1, acc, 0, 0, 0);
#pragma unroll
    for (int e = 0; e < 4; ++e) sh.f.S[4 * lq + e][jb + lm] = acc[e] * ATTN_SCALE;
  }
  __syncthreads();
  const int row = tid >> 4, t16 = tid & 15;
  const int i = i0 + row;
  const int nj = ntiles << 4;
  float m = -INFINITY;
  for (int s = 0; (s << 6) < nj; ++s) {
    int j4 = (t16 << 2) + (s << 6);
    float4 v = *(const float4*)&sh.f.S[row][j4];
    if (j4 + 0 <= i) m = fmaxf(m, v.x);
    if (j4 + 1 <= i) m = fmaxf(m, v.y);
    if (j4 + 2 <= i) m = fmaxf(m, v.z);
    if (j4 + 3 <= i) m = fmaxf(m, v.w);
  }
#pragma unroll
  for (int o = 8; o; o >>= 1) m = fmaxf(m, __shfl_xor(m, o, 16));
  float sum = 0.f;
  for (int s = 0; (s << 6) < nj; ++s) {
    int j4 = (t16 << 2) + (s << 6);
    float4 v = *(const float4*)&sh.f.S[row][j4];
    v.x = (j4 + 0 <= i) ? __expf(v.x - m) : 0.f;
    v.y = (j4 + 1 <= i) ? __expf(v.y - m) : 0.f;
    v.z = (j4 + 2 <= i) ? __expf(v.z - m) : 0.f;
    v.w = (j4 + 3 <= i) ? __expf(v.w - m) : 0.f;
    sum += v.x + v.y + v.z + v.w;
    *(float4*)&sh.f.S[row][j4] = v;
  }
#pragma unroll
  for (int o = 8; o; o >>= 1) sum += __shfl_xor(sum, o, 16);
  const float inv = 1.f / sum;
  float* arow2 = attn + (size_t)h * 262144 + (size_t)i * 512;
  ushort* abrow = attn_b + (size_t)i * 8192 + (size_t)h * 512;
  for (int s = 0; s < 8; ++s) {
    int j4 = (t16 << 2) + (s << 6);
    float4 o4 = {0.f, 0.f, 0.f, 0.f};
    if (j4 < nj) {
      float4 v = *(const float4*)&sh.f.S[row][j4];
      o4.x = v.x * inv;
      o4.y = v.y * inv;
      o4.z = v.z * inv;
      o4.w = v.w * inv;
    }
    *(float4*)(arow2 + j4) = o4;  // exact zeros above diagonal
    ushort4v p4;
    p4.x = f2bf(o4.x); p4.y = f2bf(o4.y); p4.z = f2bf(o4.z); p4.w = f2bf(o4.w);
    *(ushort4v*)&sh.f.P[row][j4] = p4;
    *(ushort4v*)(abrow + j4) = p4;  // bf16 attn copy for tker
  }
  __syncthreads();
  const int dbase = wave << 4;
  floatx4 acc2 = {0.f, 0.f, 0.f, 0.f};
  const ushort* svrow = svT + (size_t)((kv << 6) + dbase + lm) * 512;
  const int kmax = (nj + 31) & ~31;  // P zero-filled to 512
  for (int kt = 0; kt < kmax; kt += 32) {
    bf16x8 pa = *(const bf16x8*)&sh.f.P[lm][kt + lq * 8];
    bf16x8 pb = *(const bf16x8*)(svrow + kt + lq * 8);
    acc2 = __builtin_amdgcn_mfma_f32_16x16x32_bf16(pa, pb, acc2, 0, 0, 0);
  }
#pragma unroll
  for (int e = 0; e < 4; ++e)
    asym[(size_t)(i0 + 4 * lq + e) * 1024 + (h << 6) + dbase + lm] = acc2[e];
}

// ---------------------------------------------------------------------------
// tker+combine via MFMA: ONE i per block (512 blocks), dual accumulators.
// ---------------------------------------------------------------------------
__global__ __launch_bounds__(256) void tker_combine(const ushort* __restrict__ attn_b,
                                                    const ushort* __restrict__ rel_bT,
                                                    const float* __restrict__ asym,
                                                    const float* __restrict__ wr,
                                                    ushort* __restrict__ attb) {
  const int i = blockIdx.x;
  const int tid = threadIdx.x, wave = tid >> 6, lane = tid & 63;
  const int lm = lane & 15, lq = lane >> 4;
  __shared__ float Ts[4][16][17];
  floatx4 acc0 = {0.f, 0.f, 0.f, 0.f}, acc1 = {0.f, 0.f, 0.f, 0.f};
  const ushort* arow = attn_b + (size_t)i * 8192 + (size_t)lm * 512;  // h = lm
  const ushort* brow = rel_bT + (size_t)i * 8192 + (size_t)lm * 512;  // r = lm
  const int ktiles = (i >> 5) + 1;  // attn_b is exactly 0 for j > i
  int kt = wave;
  for (; kt + 4 < ktiles; kt += 8) {
    int k0 = (kt << 5) + lq * 8, k1 = ((kt + 4) << 5) + lq * 8;
    bf16x8 a0 = *(const bf16x8*)(arow + k0);
    bf16x8 b0 = *(const bf16x8*)(brow + k0);
    bf16x8 a1 = *(const bf16x8*)(arow + k1);
    bf16x8 b1 = *(const bf16x8*)(brow + k1);
    acc0 = __builtin_amdgcn_mfma_f32_16x16x32_bf16(a0, b0, acc0, 0, 0, 0);
    acc1 = __builtin_amdgcn_mfma_f32_16x16x32_bf16(a1, b1, acc1, 0, 0, 0);
  }
  if (kt < ktiles) {
    int k0 = (kt << 5) + lq * 8;
    bf16x8 a0 = *(const bf16x8*)(arow + k0);
    bf16x8 b0 = *(const bf16x8*)(brow + k0);
    acc0 = __builtin_amdgcn_mfma_f32_16x16x32_bf16(a0, b0, acc0, 0, 0, 0);
  }
  acc0 = acc0 + acc1;
  // C layout: col(lm)=r, row(4*lq+e)=h
#pragma unroll
  for (int e = 0; e < 4; ++e) Ts[wave][4 * lq + e][lm] = acc0[e];
  __syncthreads();
  const int hc = tid >> 4, d4 = (tid & 15) << 2;
  float4 o = *(const float4*)(asym + (size_t)i * 1024 + (hc << 6) + d4);
#pragma unroll
  for (int rr = 0; rr < 16; ++rr) {
    float tv = Ts[0][hc][rr] + Ts[1][hc][rr] + Ts[2][hc][rr] + Ts[3][hc][rr];
    float4 w4 = *(const float4*)(wr + (size_t)rr * 1024 + (hc << 6) + d4);
    o.x = fmaf(tv, w4.x, o.x);
    o.y = fmaf(tv, w4.y, o.y);
    o.z = fmaf(tv, w4.z, o.z);
    o.w = fmaf(tv, w4.w, o.w);
  }
  ushort4v ob;
  ob.x = f2bf(o.x); ob.y = f2bf(o.y); ob.z = f2bf(o.z); ob.w = f2bf(o.w);
  *(ushort4v*)(attb + (size_t)i * 1024 + (hc << 6) + d4) = ob;
}

// ---------------------------------------------------------------------------
// out = attb @ wo: 64x32 tiles, BK=128, double-buffered gload_lds + swizzle
// (same 2-phase structure as proj).
// ---------------------------------------------------------------------------
__global__ __launch_bounds__(256) void out_mfma(const ushort* __restrict__ attb,
                                                const ushort* __restrict__ woT,
                                                float* __restrict__ out) {
  __shared__ ushort As[2][64][128];
  __shared__ ushort Bs[2][32][128];
  const int bn = blockIdx.x << 5, bm = blockIdx.y << 6;
  const int tid = threadIdx.x;
  const int lane = tid & 63;
  const int wid = tid >> 6;
  const int wy = (tid >> 7) & 1, wx = (tid >> 6) & 1;
  const int lm = lane & 15, lq = lane >> 4;
  const int lrow = lane >> 4, lcol = lane & 15;
  const int arow = 32 * wy + lm;
  const int brow = 16 * wx + lm;
  const int aswz = (arow & 7) << 3;
  const int bswz = (brow & 7) << 3;
  floatx4 acc[2] = {};

  auto stage = [&](int buf, int k0) {
#pragma unroll
    for (int c = 0; c < 4; ++c) {
      int row = 16 * wid + 4 * c + lrow;
      int cc = lcol ^ (row & 7);
      gload16(attb + (size_t)(bm + row) * 1024 + k0 + cc * 8,
              &As[buf][16 * wid + 4 * c][0]);
    }
#pragma unroll
    for (int c = 0; c < 2; ++c) {
      int row = 8 * wid + 4 * c + lrow;
      int cc = lcol ^ (row & 7);
      gload16(woT + (size_t)(bn + row) * 1024 + k0 + cc * 8,
              &Bs[buf][8 * wid + 4 * c][0]);
    }
  };
  auto compute = [&](int buf) {
#pragma unroll
    for (int kh = 0; kh < 4; ++kh) {
      int col = kh * 32 + lq * 8;
      bf16x8 a0 = *(const bf16x8*)&As[buf][arow][col ^ aswz];
      bf16x8 a1 = *(const bf16x8*)&As[buf][arow + 16][col ^ aswz];
      bf16x8 b0 = *(const bf16x8*)&Bs[buf][brow][col ^ bswz];
      acc[0] = __builtin_amdgcn_mfma_f32_16x16x32_bf16(a0, b0, acc[0], 0, 0, 0);
      acc[1] = __builtin_amdgcn_mfma_f32_16x16x32_bf16(a1, b0, acc[1], 0, 0, 0);
    }
  };

  stage(0, 0);
  __syncthreads();
  int buf = 0;
  for (int k0 = 128; k0 < 1024; k0 += 128) {
    stage(buf ^ 1, k0);
    compute(buf);
    __syncthreads();
    buf ^= 1;
  }
  compute(buf);

#pragma unroll
  for (int sy = 0; sy < 2; ++sy)
#pragma unroll
    for (int e = 0; e < 4; ++e) {
      int row = bm + 32 * wy + 16 * sy + 4 * lq + e;
      int col = bn + 16 * wx + lm;
      out[(size_t)row * 1024 + col] = acc[sy][e];
    }
}

extern "C" void kernel_launch(void* const* d_in, const int* in_sizes, int n_in,
                              void* d_out, int out_size, void* d_ws, size_t ws_size,
                              hipStream_t stream) {
  const float* x       = (const float*)d_in[0];
  const float* symbols = (const float*)d_in[1];
  const float* fcos    = (const float*)d_in[2];
  const float* fsin    = (const float*)d_in[3];
  const float* wq_attn = (const float*)d_in[4];
  const float* wk_attn = (const float*)d_in[5];
  const float* wq_rel  = (const float*)d_in[6];
  const float* wk_rel  = (const float*)d_in[7];
  const float* wr      = (const float*)d_in[8];
  const float* wv      = (const float*)d_in[9];
  const float* wo      = (const float*)d_in[10];

  float* out  = (float*)d_out;   // 512*1024
  float* attn = out + 524288;    // 16*512*512
  float* rel  = attn + 4194304;  // 512*512*16

  char* wsb = (char*)d_ws;
  const size_t KB = 1024;
  ushort* xb     = (ushort*)(wsb);                 // 1 MB
  ushort* symb   = (ushort*)(wsb + 1024 * KB);     // 1 MB
  ushort* wqT    = (ushort*)(wsb + 2048 * KB);     // 2 MB
  ushort* wkT    = (ushort*)(wsb + 4096 * KB);     // 0.5 MB
  ushort* wqrT   = (ushort*)(wsb + 4608 * KB);     // 2 MB
  ushort* wkrT   = (ushort*)(wsb + 6656 * KB);     // 2 MB
  ushort* wvT    = (ushort*)(wsb + 8704 * KB);     // 0.5 MB
  ushort* woT    = (ushort*)(wsb + 9216 * KB);     // 2 MB
  ushort* qb     = (ushort*)(wsb + 11264 * KB);    // 1 MB
  ushort* kb     = (ushort*)(wsb + 12288 * KB);    // 0.25 MB
  ushort* qrb    = (ushort*)(wsb + 12544 * KB);    // 1 MB
  ushort* krb    = (ushort*)(wsb + 13568 * KB);    // 1 MB
  ushort* svT    = (ushort*)(wsb + 14592 * KB);    // 0.25 MB
  float*  asym   = (float*)(wsb + 14848 * KB);     // 2 MB
  ushort* attb   = (ushort*)(wsb + 16896 * KB);    // 1 MB
  ushort* rel_bT = (ushort*)(wsb + 17920 * KB);    // 8 MB
  ushort* attn_b = (ushort*)(wsb + 26112 * KB);    // 8 MB

  prep_kernel<<<dim3(32, 32, 7), 256, 0, stream>>>(x, symbols, wq_attn, wk_attn,
                                                   wq_rel, wk_rel, wv, wo,
                                                   xb, symb, wqT, wkT, wqrT, wkrT, wvT, woT);
  proj_mfma<<<dim3(32, 8, 5), 256, 0, stream>>>(xb, symb, wqT, wkT, wqrT, wkrT, wvT,
                                                qb, kb, qrb, krb, svT, fcos, fsin);
  relflash_kernel<<<dim3(768), 256, 0, stream>>>(qb, kb, svT, qrb, krb, attn, attn_b,
                                                 asym, rel, rel_bT);
  tker_combine<<<dim3(512), 256, 0, stream>>>(attn_b, rel_bT, asym, wr, attb);
  out_mfma<<<dim3(32, 8), 256, 0, stream>>>(attb, woT, out);
}

// Round 9
// 143.356 us; speedup vs baseline: 1.0594x; 1.0594x over previous
//
#include <hip/hip_runtime.h>
#include <math.h>

// B=1, L=512, D=1024, NH=16, NKV=4, NR=16, HD=RD=64
#define ATTN_SCALE 0.125f
#define REL_SCALE 0.125f

using ushort = unsigned short;
using bf16x8 = __attribute__((ext_vector_type(8))) __bf16;
using floatx4 = __attribute__((ext_vector_type(4))) float;
using ushort8 = __attribute__((ext_vector_type(8))) ushort;
using ushort4v = __attribute__((ext_vector_type(4))) ushort;

__device__ __forceinline__ ushort f2bf(float x) {
  unsigned int u = __builtin_bit_cast(unsigned int, x);
  u += 0x7fffu + ((u >> 16) & 1u);  // RNE
  return (ushort)(u >> 16);
}

// global -> LDS direct DMA, 16B per lane. LDS dest is wave-uniform base +
// lane*16 (HW semantics); global src is per-lane.
__device__ __forceinline__ void gload16(const ushort* src, ushort* lds) {
  __builtin_amdgcn_global_load_lds(
      (const __attribute__((address_space(1))) void*)src,
      (__attribute__((address_space(3))) void*)lds, 16, 0, 0);
}

// ---------------------------------------------------------------------------
// prep: z=0..5 weight transpose+convert; one-pass float4 loads, ushort4 (8B)
//       vectorized stores. z=6 x/symbols fp32->bf16.
// ---------------------------------------------------------------------------
__global__ __launch_bounds__(256) void prep_kernel(
    const float* __restrict__ x, const float* __restrict__ sym,
    const float* __restrict__ wq, const float* __restrict__ wk,
    const float* __restrict__ wqr, const float* __restrict__ wkr,
    const float* __restrict__ wv, const float* __restrict__ wo,
    ushort* __restrict__ xb, ushort* __restrict__ symb,
    ushort* __restrict__ wqT, ushort* __restrict__ wkT, ushort* __restrict__ wqrT,
    ushort* __restrict__ wkrT, ushort* __restrict__ wvT, ushort* __restrict__ woT) {
  if (blockIdx.z == 6) {
    int b = blockIdx.y * 32 + blockIdx.x;
    if (b >= 512) return;
    int idx = b * 256 + threadIdx.x;
    int i4 = idx << 2;
    float4 v = *(const float4*)(x + i4);
    uint2 o;
    o.x = (unsigned)f2bf(v.x) | ((unsigned)f2bf(v.y) << 16);
    o.y = (unsigned)f2bf(v.z) | ((unsigned)f2bf(v.w) << 16);
    *(uint2*)(xb + i4) = o;
    float4 w = *(const float4*)(sym + i4);
    o.x = (unsigned)f2bf(w.x) | ((unsigned)f2bf(w.y) << 16);
    o.y = (unsigned)f2bf(w.z) | ((unsigned)f2bf(w.w) << 16);
    *(uint2*)(symb + i4) = o;
    return;
  }
  __shared__ ushort t[32][44];
  const float* in;
  ushort* out;
  int N;
  switch (blockIdx.z) {
    case 0: in = wq;  out = wqT;  N = 1024; break;
    case 1: in = wk;  out = wkT;  N = 256;  break;
    case 2: in = wqr; out = wqrT; N = 1024; break;
    case 3: in = wkr; out = wkrT; N = 1024; break;
    case 4: in = wv;  out = wvT;  N = 256;  break;
    default: in = wo; out = woT;  N = 1024; break;
  }
  int n0 = blockIdx.x << 5;
  if (n0 >= N) return;
  int k0 = blockIdx.y << 5;
  {
    int kr = threadIdx.x >> 3, nq = threadIdx.x & 7;
    float4 v = *(const float4*)(in + (size_t)(k0 + kr) * N + n0 + (nq << 2));
    ushort4v c;
    c.x = f2bf(v.x); c.y = f2bf(v.y); c.z = f2bf(v.z); c.w = f2bf(v.w);
    *(ushort4v*)&t[kr][nq << 2] = c;
  }
  __syncthreads();
  {
    int nr = threadIdx.x >> 3, kq = threadIdx.x & 7;
    ushort4v c;
    c.x = t[(kq << 2) + 0][nr];
    c.y = t[(kq << 2) + 1][nr];
    c.z = t[(kq << 2) + 2][nr];
    c.w = t[(kq << 2) + 3][nr];
    *(ushort4v*)(out + (size_t)(n0 + nr) * 1024 + k0 + (kq << 2)) = c;
  }
}

// ---------------------------------------------------------------------------
// proj: 64x32 tiles, BK=128, single-buffered global_load_lds(16B) staging
// into LINEAR LDS with both-sides XOR swizzle (source colchunk ^= row&7;
// read col ^= (row&7)<<3) -> conflict-free ds_read_b128, zero VGPR staging.
// Single buffer keeps LDS at 24KB -> ~6 blocks/CU TLP (dbuf at 48KB measured
// -8us regression, R8).
// z = {q(+rope), k(+rope), qr, kr, sv(->svT)}.
// ---------------------------------------------------------------------------
__global__ __launch_bounds__(256) void proj_mfma(
    const ushort* __restrict__ xb, const ushort* __restrict__ symb,
    const ushort* __restrict__ wqT, const ushort* __restrict__ wkT,
    const ushort* __restrict__ wqrT, const ushort* __restrict__ wkrT,
    const ushort* __restrict__ wvT,
    ushort* __restrict__ qb, ushort* __restrict__ kb, ushort* __restrict__ qrb,
    ushort* __restrict__ krb, ushort* __restrict__ svT,
    const float* __restrict__ fcos, const float* __restrict__ fsin) {
  __shared__ ushort As[64][128];
  __shared__ ushort Bs[32][128];
  const int z = blockIdx.z;
  const ushort* A = xb;
  const ushort* Bt;
  ushort* C;
  int N;
  switch (z) {
    case 0: Bt = wqT;  C = qb;  N = 1024; break;
    case 1: Bt = wkT;  C = kb;  N = 256;  break;
    case 2: Bt = wqrT; C = qrb; N = 1024; break;
    case 3: Bt = wkrT; C = krb; N = 1024; break;
    default: A = symb; Bt = wvT; C = svT; N = 256; break;
  }
  const int bn = blockIdx.x << 5;
  if (bn >= N) return;
  const int bm = blockIdx.y << 6;
  const int tid = threadIdx.x;
  const int lane = tid & 63;
  const int wid = tid >> 6;  // wave 0..3
  const int wy = (tid >> 7) & 1, wx = (tid >> 6) & 1;
  const int lm = lane & 15, lq = lane >> 4;
  const int lrow = lane >> 4, lcol = lane & 15;  // within 1KB DMA chunk
  const int arow = 32 * wy + lm;
  const int brow = 16 * wx + lm;
  const int aswz = (arow & 7) << 3;  // (arow+16)&7 == arow&7
  const int bswz = (brow & 7) << 3;
  floatx4 acc[2] = {};
  for (int k0 = 0; k0 < 1024; k0 += 128) {
    __syncthreads();  // previous iter's LDS reads done
    // A: wave wid stages rows [16*wid, 16*wid+16): 4 x 1KB chunks
#pragma unroll
    for (int c = 0; c < 4; ++c) {
      int row = 16 * wid + 4 * c + lrow;
      int cc = lcol ^ (row & 7);
      gload16(A + (size_t)(bm + row) * 1024 + k0 + cc * 8, &As[16 * wid + 4 * c][0]);
    }
    // B: wave wid stages rows [8*wid, 8*wid+8): 2 x 1KB chunks
#pragma unroll
    for (int c = 0; c < 2; ++c) {
      int row = 8 * wid + 4 * c + lrow;
      int cc = lcol ^ (row & 7);
      gload16(Bt + (size_t)(bn + row) * 1024 + k0 + cc * 8, &Bs[8 * wid + 4 * c][0]);
    }
    __syncthreads();  // compiler drains vmcnt(0) before barrier -> LDS ready
#pragma unroll
    for (int kh = 0; kh < 4; ++kh) {
      int col = kh * 32 + lq * 8;
      bf16x8 a0 = *(const bf16x8*)&As[arow][col ^ aswz];
      bf16x8 a1 = *(const bf16x8*)&As[arow + 16][col ^ aswz];
      bf16x8 b0 = *(const bf16x8*)&Bs[brow][col ^ bswz];
      acc[0] = __builtin_amdgcn_mfma_f32_16x16x32_bf16(a0, b0, acc[0], 0, 0, 0);
      acc[1] = __builtin_amdgcn_mfma_f32_16x16x32_bf16(a1, b0, acc[1], 0, 0, 0);
    }
  }
  if (z <= 1) {
    // fused RoPE: lanes lm, lm^1 hold the (even,odd) pair of d
#pragma unroll
    for (int sy = 0; sy < 2; ++sy)
#pragma unroll
      for (int e = 0; e < 4; ++e) {
        int row = bm + 32 * wy + 16 * sy + 4 * lq + e;
        int col = bn + 16 * wx + lm;
        float v = acc[sy][e];
        float pv = __shfl_xor(v, 1);
        int d = col & 63, p = d >> 1;
        float c = fcos[(row << 5) + p], s = fsin[(row << 5) + p];
        float o = (d & 1) ? fmaf(pv, s, v * c) : fmaf(v, c, -pv * s);
        C[(size_t)row * N + col] = f2bf(o);
      }
  } else if (z == 4) {
#pragma unroll
    for (int sy = 0; sy < 2; ++sy)
#pragma unroll
      for (int e = 0; e < 4; ++e) {
        int row = bm + 32 * wy + 16 * sy + 4 * lq + e;
        int col = bn + 16 * wx + lm;
        svT[(size_t)col * 512 + row] = f2bf(acc[sy][e]);
      }
  } else {
#pragma unroll
    for (int sy = 0; sy < 2; ++sy)
#pragma unroll
      for (int e = 0; e < 4; ++e) {
        int row = bm + 32 * wy + 16 * sy + 4 * lq + e;
        int col = bn + 16 * wx + lm;
        C[(size_t)row * N + col] = f2bf(acc[sy][e]);
      }
  }
}

// ---------------------------------------------------------------------------
// relflash: bx<512 -> flash; bx>=512 -> relations (LDS-staged dense rel_bT).
// ---------------------------------------------------------------------------
struct FlashSh {
  float S[16][516];
  ushort P[16][520];
};
union RelFlashSh {
  FlashSh f;
  ushort RT[32 * 648];  // [i(32)][r(16)][j(40 padded, 32 used)]
};

__global__ __launch_bounds__(256) void relflash_kernel(
    const ushort* __restrict__ qb, const ushort* __restrict__ kb,
    const ushort* __restrict__ svT, const ushort* __restrict__ qrb,
    const ushort* __restrict__ krb, float* __restrict__ attn,
    ushort* __restrict__ attn_b, float* __restrict__ asym,
    float* __restrict__ rel, ushort* __restrict__ rel_bT) {
  __shared__ RelFlashSh sh;
  const int bx = blockIdx.x;
  const int tid = threadIdx.x, wave = tid >> 6, lane = tid & 63;
  const int lm = lane & 15, lq = lane >> 4;
  if (bx >= 512) {
    // ---- relations ----
    const int b = bx - 512;
    const int bi0 = (b >> 4) << 5, bj0 = (b & 15) << 5;
    const int ib = bi0 + ((wave >> 1) << 4), jb = bj0 + ((wave & 1) << 4);
    const int il0 = (wave >> 1) << 4, jl0 = (wave & 1) << 4;
    const ushort* qrow = qrb + (size_t)(ib + lm) * 1024 + lq * 8;
    const ushort* krow = krb + (size_t)(jb + lm) * 1024 + lq * 8;
    floatx4 acc[16];
#pragma unroll
    for (int rq = 0; rq < 4; ++rq) {
#pragma unroll
      for (int rr = 0; rr < 4; ++rr) {
        int r = (rq << 2) + rr;
        int roff = r << 6;
        bf16x8 a0 = *(const bf16x8*)(qrow + roff);
        bf16x8 a1 = *(const bf16x8*)(qrow + roff + 32);
        bf16x8 b0 = *(const bf16x8*)(krow + roff);
        bf16x8 b1 = *(const bf16x8*)(krow + roff + 32);
        floatx4 t = {0.f, 0.f, 0.f, 0.f};
        t = __builtin_amdgcn_mfma_f32_16x16x32_bf16(a0, b0, t, 0, 0, 0);
        t = __builtin_amdgcn_mfma_f32_16x16x32_bf16(a1, b1, t, 0, 0, 0);
        acc[r] = t;
      }
    }
#pragma unroll
    for (int e = 0; e < 4; ++e) {
      int i = ib + 4 * lq + e, j = jb + lm;
      int il = il0 + 4 * lq + e, jl = jl0 + lm;
      float* dst = rel + ((size_t)i * 512 + j) * 16;
      ushort* rt = &sh.RT[il * 648 + jl];
#pragma unroll
      for (int q = 0; q < 4; ++q) {
        float4 v = make_float4(acc[4 * q + 0][e] * REL_SCALE,
                               acc[4 * q + 1][e] * REL_SCALE,
                               acc[4 * q + 2][e] * REL_SCALE,
                               acc[4 * q + 3][e] * REL_SCALE);
        *(float4*)(dst + (q << 2)) = v;
        rt[(4 * q + 0) * 40] = f2bf(v.x);
        rt[(4 * q + 1) * 40] = f2bf(v.y);
        rt[(4 * q + 2) * 40] = f2bf(v.z);
        rt[(4 * q + 3) * 40] = f2bf(v.w);
      }
    }
    __syncthreads();
    {
      const int r = lane >> 2, jq = lane & 3;
#pragma unroll
      for (int it2 = 0; it2 < 8; ++it2) {
        int il = (it2 << 2) + wave;
        ushort8 v = *(const ushort8*)&sh.RT[il * 648 + r * 40 + (jq << 3)];
        *(ushort8*)(rel_bT + (size_t)(bi0 + il) * 8192 + (size_t)r * 512 + bj0 +
                    (jq << 3)) = v;
      }
    }
    return;
  }
  // ---- flash ----
  const int h = bx >> 5, it = 31 - (bx & 31);  // longest tiles dispatched first
  const int i0 = it << 4, kv = h >> 2;
  const int ntiles = it + 1;
  const ushort* qrow = qb + (size_t)(i0 + lm) * 1024 + (h << 6) + lq * 8;
  bf16x8 a0 = *(const bf16x8*)(qrow);
  bf16x8 a1 = *(const bf16x8*)(qrow + 32);
  for (int jt = wave; jt < ntiles; jt += 4) {
    int jb = jt << 4;
    const ushort* krow = kb + (size_t)(jb + lm) * 256 + (kv << 6) + lq * 8;
    bf16x8 b0 = *(const bf16x8*)(krow);
    bf16x8 b1 = *(const bf16x8*)(krow + 32);
    floatx4 acc = {0.f, 0.f, 0.f, 0.f};
    acc = __builtin_amdgcn_mfma_f32_16x16x32_bf16(a0, b0, acc, 0, 0, 0);
    acc = __builtin_amdgcn_mfma_f32_16x16x32_bf16(a1, b1, acc, 0, 0, 0);
#pragma unroll
    for (int e = 0; e < 4; ++e) sh.f.S[4 * lq + e][jb + lm] = acc[e] * ATTN_SCALE;
  }
  __syncthreads();
  const int row = tid >> 4, t16 = tid & 15;
  const int i = i0 + row;
  const int nj = ntiles << 4;
  float m = -INFINITY;
  for (int s = 0; (s << 6) < nj; ++s) {
    int j4 = (t16 << 2) + (s << 6);
    float4 v = *(const float4*)&sh.f.S[row][j4];
    if (j4 + 0 <= i) m = fmaxf(m, v.x);
    if (j4 + 1 <= i) m = fmaxf(m, v.y);
    if (j4 + 2 <= i) m = fmaxf(m, v.z);
    if (j4 + 3 <= i) m = fmaxf(m, v.w);
  }
#pragma unroll
  for (int o = 8; o; o >>= 1) m = fmaxf(m, __shfl_xor(m, o, 16));
  float sum = 0.f;
  for (int s = 0; (s << 6) < nj; ++s) {
    int j4 = (t16 << 2) + (s << 6);
    float4 v = *(const float4*)&sh.f.S[row][j4];
    v.x = (j4 + 0 <= i) ? __expf(v.x - m) : 0.f;
    v.y = (j4 + 1 <= i) ? __expf(v.y - m) : 0.f;
    v.z = (j4 + 2 <= i) ? __expf(v.z - m) : 0.f;
    v.w = (j4 + 3 <= i) ? __expf(v.w - m) : 0.f;
    sum += v.x + v.y + v.z + v.w;
    *(float4*)&sh.f.S[row][j4] = v;
  }
#pragma unroll
  for (int o = 8; o; o >>= 1) sum += __shfl_xor(sum, o, 16);
  const float inv = 1.f / sum;
  float* arow2 = attn + (size_t)h * 262144 + (size_t)i * 512;
  ushort* abrow = attn_b + (size_t)i * 8192 + (size_t)h * 512;
  for (int s = 0; s < 8; ++s) {
    int j4 = (t16 << 2) + (s << 6);
    float4 o4 = {0.f, 0.f, 0.f, 0.f};
    if (j4 < nj) {
      float4 v = *(const float4*)&sh.f.S[row][j4];
      o4.x = v.x * inv;
      o4.y = v.y * inv;
      o4.z = v.z * inv;
      o4.w = v.w * inv;
    }
    *(float4*)(arow2 + j4) = o4;  // exact zeros above diagonal
    ushort4v p4;
    p4.x = f2bf(o4.x); p4.y = f2bf(o4.y); p4.z = f2bf(o4.z); p4.w = f2bf(o4.w);
    *(ushort4v*)&sh.f.P[row][j4] = p4;
    *(ushort4v*)(abrow + j4) = p4;  // bf16 attn copy for tker
  }
  __syncthreads();
  const int dbase = wave << 4;
  floatx4 acc2 = {0.f, 0.f, 0.f, 0.f};
  const ushort* svrow = svT + (size_t)((kv << 6) + dbase + lm) * 512;
  const int kmax = (nj + 31) & ~31;  // P zero-filled to 512
  for (int kt = 0; kt < kmax; kt += 32) {
    bf16x8 pa = *(const bf16x8*)&sh.f.P[lm][kt + lq * 8];
    bf16x8 pb = *(const bf16x8*)(svrow + kt + lq * 8);
    acc2 = __builtin_amdgcn_mfma_f32_16x16x32_bf16(pa, pb, acc2, 0, 0, 0);
  }
#pragma unroll
  for (int e = 0; e < 4; ++e)
    asym[(size_t)(i0 + 4 * lq + e) * 1024 + (h << 6) + dbase + lm] = acc2[e];
}

// ---------------------------------------------------------------------------
// tker+combine via MFMA: ONE i per block (512 blocks), dual accumulators.
// ---------------------------------------------------------------------------
__global__ __launch_bounds__(256) void tker_combine(const ushort* __restrict__ attn_b,
                                                    const ushort* __restrict__ rel_bT,
                                                    const float* __restrict__ asym,
                                                    const float* __restrict__ wr,
                                                    ushort* __restrict__ attb) {
  const int i = blockIdx.x;
  const int tid = threadIdx.x, wave = tid >> 6, lane = tid & 63;
  const int lm = lane & 15, lq = lane >> 4;
  __shared__ float Ts[4][16][17];
  floatx4 acc0 = {0.f, 0.f, 0.f, 0.f}, acc1 = {0.f, 0.f, 0.f, 0.f};
  const ushort* arow = attn_b + (size_t)i * 8192 + (size_t)lm * 512;  // h = lm
  const ushort* brow = rel_bT + (size_t)i * 8192 + (size_t)lm * 512;  // r = lm
  const int ktiles = (i >> 5) + 1;  // attn_b is exactly 0 for j > i
  int kt = wave;
  for (; kt + 4 < ktiles; kt += 8) {
    int k0 = (kt << 5) + lq * 8, k1 = ((kt + 4) << 5) + lq * 8;
    bf16x8 a0 = *(const bf16x8*)(arow + k0);
    bf16x8 b0 = *(const bf16x8*)(brow + k0);
    bf16x8 a1 = *(const bf16x8*)(arow + k1);
    bf16x8 b1 = *(const bf16x8*)(brow + k1);
    acc0 = __builtin_amdgcn_mfma_f32_16x16x32_bf16(a0, b0, acc0, 0, 0, 0);
    acc1 = __builtin_amdgcn_mfma_f32_16x16x32_bf16(a1, b1, acc1, 0, 0, 0);
  }
  if (kt < ktiles) {
    int k0 = (kt << 5) + lq * 8;
    bf16x8 a0 = *(const bf16x8*)(arow + k0);
    bf16x8 b0 = *(const bf16x8*)(brow + k0);
    acc0 = __builtin_amdgcn_mfma_f32_16x16x32_bf16(a0, b0, acc0, 0, 0, 0);
  }
  acc0 = acc0 + acc1;
  // C layout: col(lm)=r, row(4*lq+e)=h
#pragma unroll
  for (int e = 0; e < 4; ++e) Ts[wave][4 * lq + e][lm] = acc0[e];
  __syncthreads();
  const int hc = tid >> 4, d4 = (tid & 15) << 2;
  float4 o = *(const float4*)(asym + (size_t)i * 1024 + (hc << 6) + d4);
#pragma unroll
  for (int rr = 0; rr < 16; ++rr) {
    float tv = Ts[0][hc][rr] + Ts[1][hc][rr] + Ts[2][hc][rr] + Ts[3][hc][rr];
    float4 w4 = *(const float4*)(wr + (size_t)rr * 1024 + (hc << 6) + d4);
    o.x = fmaf(tv, w4.x, o.x);
    o.y = fmaf(tv, w4.y, o.y);
    o.z = fmaf(tv, w4.z, o.z);
    o.w = fmaf(tv, w4.w, o.w);
  }
  ushort4v ob;
  ob.x = f2bf(o.x); ob.y = f2bf(o.y); ob.z = f2bf(o.z); ob.w = f2bf(o.w);
  *(ushort4v*)(attb + (size_t)i * 1024 + (hc << 6) + d4) = ob;
}

// ---------------------------------------------------------------------------
// out = attb @ wo: 64x32 tiles, BK=128, single-buffered gload_lds + swizzle
// (same staging structure as proj).
// ---------------------------------------------------------------------------
__global__ __launch_bounds__(256) void out_mfma(const ushort* __restrict__ attb,
                                                const ushort* __restrict__ woT,
                                                float* __restrict__ out) {
  __shared__ ushort As[64][128];
  __shared__ ushort Bs[32][128];
  const int bn = blockIdx.x << 5, bm = blockIdx.y << 6;
  const int tid = threadIdx.x;
  const int lane = tid & 63;
  const int wid = tid >> 6;
  const int wy = (tid >> 7) & 1, wx = (tid >> 6) & 1;
  const int lm = lane & 15, lq = lane >> 4;
  const int lrow = lane >> 4, lcol = lane & 15;
  const int arow = 32 * wy + lm;
  const int brow = 16 * wx + lm;
  const int aswz = (arow & 7) << 3;
  const int bswz = (brow & 7) << 3;
  floatx4 acc[2] = {};
  for (int k0 = 0; k0 < 1024; k0 += 128) {
    __syncthreads();
#pragma unroll
    for (int c = 0; c < 4; ++c) {
      int row = 16 * wid + 4 * c + lrow;
      int cc = lcol ^ (row & 7);
      gload16(attb + (size_t)(bm + row) * 1024 + k0 + cc * 8, &As[16 * wid + 4 * c][0]);
    }
#pragma unroll
    for (int c = 0; c < 2; ++c) {
      int row = 8 * wid + 4 * c + lrow;
      int cc = lcol ^ (row & 7);
      gload16(woT + (size_t)(bn + row) * 1024 + k0 + cc * 8, &Bs[8 * wid + 4 * c][0]);
    }
    __syncthreads();
#pragma unroll
    for (int kh = 0; kh < 4; ++kh) {
      int col = kh * 32 + lq * 8;
      bf16x8 a0 = *(const bf16x8*)&As[arow][col ^ aswz];
      bf16x8 a1 = *(const bf16x8*)&As[arow + 16][col ^ aswz];
      bf16x8 b0 = *(const bf16x8*)&Bs[brow][col ^ bswz];
      acc[0] = __builtin_amdgcn_mfma_f32_16x16x32_bf16(a0, b0, acc[0], 0, 0, 0);
      acc[1] = __builtin_amdgcn_mfma_f32_16x16x32_bf16(a1, b0, acc[1], 0, 0, 0);
    }
  }
#pragma unroll
  for (int sy = 0; sy < 2; ++sy)
#pragma unroll
    for (int e = 0; e < 4; ++e) {
      int row = bm + 32 * wy + 16 * sy + 4 * lq + e;
      int col = bn + 16 * wx + lm;
      out[(size_t)row * 1024 + col] = acc[sy][e];
    }
}

extern "C" void kernel_launch(void* const* d_in, const int* in_sizes, int n_in,
                              void* d_out, int out_size, void* d_ws, size_t ws_size,
                              hipStream_t stream) {
  const float* x       = (const float*)d_in[0];
  const float* symbols = (const float*)d_in[1];
  const float* fcos    = (const float*)d_in[2];
  const float* fsin    = (const float*)d_in[3];
  const float* wq_attn = (const float*)d_in[4];
  const float* wk_attn = (const float*)d_in[5];
  const float* wq_rel  = (const float*)d_in[6];
  const float* wk_rel  = (const float*)d_in[7];
  const float* wr      = (const float*)d_in[8];
  const float* wv      = (const float*)d_in[9];
  const float* wo      = (const float*)d_in[10];

  float* out  = (float*)d_out;   // 512*1024
  float* attn = out + 524288;    // 16*512*512
  float* rel  = attn + 4194304;  // 512*512*16

  char* wsb = (char*)d_ws;
  const size_t KB = 1024;
  ushort* xb     = (ushort*)(wsb);                 // 1 MB
  ushort* symb   = (ushort*)(wsb + 1024 * KB);     // 1 MB
  ushort* wqT    = (ushort*)(wsb + 2048 * KB);     // 2 MB
  ushort* wkT    = (ushort*)(wsb + 4096 * KB);     // 0.5 MB
  ushort* wqrT   = (ushort*)(wsb + 4608 * KB);     // 2 MB
  ushort* wkrT   = (ushort*)(wsb + 6656 * KB);     // 2 MB
  ushort* wvT    = (ushort*)(wsb + 8704 * KB);     // 0.5 MB
  ushort* woT    = (ushort*)(wsb + 9216 * KB);     // 2 MB
  ushort* qb     = (ushort*)(wsb + 11264 * KB);    // 1 MB
  ushort* kb     = (ushort*)(wsb + 12288 * KB);    // 0.25 MB
  ushort* qrb    = (ushort*)(wsb + 12544 * KB);    // 1 MB
  ushort* krb    = (ushort*)(wsb + 13568 * KB);    // 1 MB
  ushort* svT    = (ushort*)(wsb + 14592 * KB);    // 0.25 MB
  float*  asym   = (float*)(wsb + 14848 * KB);     // 2 MB
  ushort* attb   = (ushort*)(wsb + 16896 * KB);    // 1 MB
  ushort* rel_bT = (ushort*)(wsb + 17920 * KB);    // 8 MB
  ushort* attn_b = (ushort*)(wsb + 26112 * KB);    // 8 MB

  prep_kernel<<<dim3(32, 32, 7), 256, 0, stream>>>(x, symbols, wq_attn, wk_attn,
                                                   wq_rel, wk_rel, wv, wo,
                                                   xb, symb, wqT, wkT, wqrT, wkrT, wvT, woT);
  proj_mfma<<<dim3(32, 8, 5), 256, 0, stream>>>(xb, symb, wqT, wkT, wqrT, wkrT, wvT,
                                                qb, kb, qrb, krb, svT, fcos, fsin);
  relflash_kernel<<<dim3(768), 256, 0, stream>>>(qb, kb, svT, qrb, krb, attn, attn_b,
                                                 asym, rel, rel_bT);
  tker_combine<<<dim3(512), 256, 0, stream>>>(attn_b, rel_bT, asym, wr, attb);
  out_mfma<<<dim3(32, 8), 256, 0, stream>>>(attb, woT, out);
}